// Round 3
// baseline (660.326 us; speedup 1.0000x reference)
//
#include <hip/hip_runtime.h>

#define GN 50000      // nodes
#define GE 800000     // edges per graph
#define HID 128
#define OUTC 64
#define NB 196        // scan blocks per graph: ceil(50000/256)
#define BSH 5         // bucket shift: 32 nodes per bucket
#define NBUCK 1563    // ceil(50000/32)

// workspace layout (float element offsets)
#define OFF_H1    0            // 6,400,000 f  (x@W1)
#define OFF_H2    6400000      // 3,200,000 f  (relu(bn(hidden))@W2) -- also aliased as pair buffers
#define OFF_DINV1 9600000      // 50,000
#define OFF_DINV2 9650000      // 50,000
#define OFF_ROW1  9700000      // 50,001 int
#define OFF_ROW2  9750004      // 50,001 int
#define OFF_CUR1  9800008      // 50,000 int
#define OFF_CUR2  9850008      // 50,000 int
#define OFF_CNT1  9900008      // 50,000 int   -- memset region start
#define OFF_CNT2  9950008      // 50,000 int
#define OFF_BN    10000008     // 512 f: sum@0 sumsq@128 scale@256 shift@384
#define OFF_SRC1  10000520     // 800,000 int
#define OFF_SRC2  10800520     // 800,000 int
#define OFF_BSUM  11600520     // 2*NB int  (per-block sums, both graphs)
#define OFF_BOFS  11601032     // 2*NB int  (scanned block offsets)
#define OFF_BCUR1 11601424     // NBUCK int (bucket cursors, graph 1)
#define OFF_BCUR2 11602987     // NBUCK int (graph 2)

__global__ __launch_bounds__(256) void count_kernel(const int* __restrict__ e1,
    const int* __restrict__ e2, int* __restrict__ cnt1, int* __restrict__ cnt2) {
  int i = blockIdx.x * 256 + threadIdx.x;
  if (i < GE) {
    atomicAdd(&cnt1[e1[GE + i]], 1);   // dst of graph 1
    atomicAdd(&cnt2[e2[GE + i]], 1);   // dst of graph 2
  }
}

// stage A: per-block sums of cnt. grid = 2*NB blocks; blockIdx.x >= NB -> graph 2
__global__ __launch_bounds__(256) void scanA_kernel(const int* __restrict__ cnt1,
    const int* __restrict__ cnt2, int* __restrict__ bsum) {
  __shared__ int lds[256];
  int b = blockIdx.x;
  int g = (b >= NB) ? 1 : 0;
  int lb = b - g * NB;
  const int* cnt = g ? cnt2 : cnt1;
  int idx = lb * 256 + threadIdx.x;
  int v = (idx < GN) ? cnt[idx] : 0;
  lds[threadIdx.x] = v;
  __syncthreads();
  for (int off = 128; off > 0; off >>= 1) {
    if (threadIdx.x < off) lds[threadIdx.x] += lds[threadIdx.x + off];
    __syncthreads();
  }
  if (threadIdx.x == 0) bsum[b] = lds[0];
}

// stage B: 1 block, exclusive-scan the NB block-sums for each graph; write totals to row[GN]
__global__ __launch_bounds__(256) void scanB_kernel(const int* __restrict__ bsum,
    int* __restrict__ bofs, int* __restrict__ row1, int* __restrict__ row2) {
  __shared__ int lds[256];
  int t = threadIdx.x;
  for (int g = 0; g < 2; ++g) {
    int v = (t < NB) ? bsum[g * NB + t] : 0;
    int orig = v;
    lds[t] = v;
    __syncthreads();
    for (int off = 1; off < 256; off <<= 1) {
      int u = (t >= off) ? lds[t - off] : 0;
      __syncthreads();
      lds[t] += u;
      __syncthreads();
    }
    if (t < NB) bofs[g * NB + t] = lds[t] - orig;   // exclusive
    if (t == NB - 1) { if (g) row2[GN] = lds[t]; else row1[GN] = lds[t]; }
    __syncthreads();
  }
}

// stage C: per-block local exclusive scan + block offset -> row/cur; dinv = rsqrt(1+cnt);
// also seed bucket cursors with row[bucket_start]
__global__ __launch_bounds__(256) void scanC_kernel(const int* __restrict__ cnt1,
    const int* __restrict__ cnt2, const int* __restrict__ bofs,
    int* __restrict__ row1, int* __restrict__ cur1, float* __restrict__ dinv1,
    int* __restrict__ row2, int* __restrict__ cur2, float* __restrict__ dinv2,
    int* __restrict__ bcur1, int* __restrict__ bcur2) {
  __shared__ int lds[256];
  int b = blockIdx.x;
  int g = (b >= NB) ? 1 : 0;
  int lb = b - g * NB;
  const int* cnt = g ? cnt2 : cnt1;
  int* row = g ? row2 : row1;
  int* cur = g ? cur2 : cur1;
  float* dinv = g ? dinv2 : dinv1;
  int* bcur = g ? bcur2 : bcur1;
  int t = threadIdx.x;
  int idx = lb * 256 + t;
  int v = (idx < GN) ? cnt[idx] : 0;
  lds[t] = v;
  __syncthreads();
  for (int off = 1; off < 256; off <<= 1) {
    int u = (t >= off) ? lds[t - off] : 0;
    __syncthreads();
    lds[t] += u;
    __syncthreads();
  }
  if (idx < GN) {
    int e = bofs[b] + lds[t] - v;   // exclusive prefix
    row[idx] = e;
    cur[idx] = e;
    dinv[idx] = rsqrtf(1.0f + (float)v);
    if ((idx & 31) == 0) bcur[idx >> BSH] = e;   // bucket cursor start
  }
}

// phase 1: bin (src,dst) pairs by dst>>BSH; appends hit bucket tails -> full-line writes
__global__ __launch_bounds__(256) void pair_scatter_kernel(const int* __restrict__ e1,
    const int* __restrict__ e2, int* __restrict__ bcur1, int* __restrict__ bcur2,
    int2* __restrict__ pair1, int2* __restrict__ pair2) {
  int i = blockIdx.x * 256 + threadIdx.x;
  if (i < GE) {
    int s1 = e1[i], d1 = e1[GE + i];
    int p1 = atomicAdd(&bcur1[d1 >> BSH], 1);
    pair1[p1] = make_int2(s1, d1);
    int s2 = e2[i], d2 = e2[GE + i];
    int p2 = atomicAdd(&bcur2[d2 >> BSH], 1);
    pair2[p2] = make_int2(s2, d2);
  }
}

// phase 2: pairs are dst-grouped -> cur scatter lands in ~2KB span per bucket
__global__ __launch_bounds__(256) void pair_fill_kernel(const int2* __restrict__ pair1,
    const int2* __restrict__ pair2, int* __restrict__ cur1, int* __restrict__ cur2,
    int* __restrict__ src1, int* __restrict__ src2) {
  int i = blockIdx.x * 256 + threadIdx.x;
  if (i < GE) {
    int2 p = pair1[i];
    int q1 = atomicAdd(&cur1[p.y], 1);
    src1[q1] = p.x;
    int2 r = pair2[i];
    int q2 = atomicAdd(&cur2[r.y], 1);
    src2[q2] = r.x;
  }
}

// C[M,128] = A[M,128] @ B[128,128]; block tile 32 rows x 64 cols (blockIdx.y selects col half)
__global__ __launch_bounds__(256) void gemm1_kernel(const float* __restrict__ A,
    const float* __restrict__ B, float* __restrict__ C) {
  __shared__ __align__(16) float wlds[128 * 64];
  __shared__ __align__(16) float alds[32 * 128];
  int t = threadIdx.x;
  int row0 = blockIdx.x * 32;
  int cb = blockIdx.y * 64;
  for (int i = t; i < 128 * 16; i += 256) {        // W tile: 128 rows x 16 float4
    int k = i >> 4, c4 = i & 15;
    ((float4*)wlds)[i] = ((const float4*)B)[k * 32 + (cb >> 2) + c4];
  }
  for (int i = t; i < 1024; i += 256) {            // A tile: 32 rows x 32 float4
    int r = i >> 5, c4 = i & 31;
    int gr = row0 + r;
    ((float4*)alds)[i] = (gr < GN) ? ((const float4*)A)[(size_t)gr * 32 + c4]
                                   : make_float4(0.f, 0.f, 0.f, 0.f);
  }
  __syncthreads();
  int j0 = (t & 15) * 4;
  int r0 = (t >> 4) * 2;
  float4 acc0 = {0, 0, 0, 0}, acc1 = {0, 0, 0, 0};
  #pragma unroll 8
  for (int k = 0; k < 128; ++k) {
    float4 w = *(const float4*)&wlds[k * 64 + j0];
    float a0 = alds[r0 * 128 + k];
    float a1 = alds[(r0 + 1) * 128 + k];
    acc0.x += a0 * w.x; acc0.y += a0 * w.y; acc0.z += a0 * w.z; acc0.w += a0 * w.w;
    acc1.x += a1 * w.x; acc1.y += a1 * w.y; acc1.z += a1 * w.z; acc1.w += a1 * w.w;
  }
  int gr0 = row0 + r0;
  if (gr0 < GN)     *(float4*)&C[(size_t)gr0 * 128 + cb + j0] = acc0;
  if (gr0 + 1 < GN) *(float4*)&C[(size_t)(gr0 + 1) * 128 + cb + j0] = acc1;
}

// C[M,64] = relu(bn(A[M,128])) @ B[128,64]
__global__ __launch_bounds__(256) void gemm2_kernel(const float* __restrict__ A,
    const float* __restrict__ B, const float* __restrict__ scale,
    const float* __restrict__ shift, float* __restrict__ C) {
  __shared__ __align__(16) float wlds[128 * 64];
  __shared__ __align__(16) float alds[32 * 128];
  __shared__ float sc[128], sh[128];
  int t = threadIdx.x;
  if (t < 128) { sc[t] = scale[t]; sh[t] = shift[t]; }
  int row0 = blockIdx.x * 32;
  for (int i = t; i < 128 * 16; i += 256)
    ((float4*)wlds)[i] = ((const float4*)B)[i];
  __syncthreads();   // sc/sh ready before prologue
  for (int i = t; i < 1024; i += 256) {
    int r = i >> 5, c4 = i & 31;
    int gr = row0 + r;
    float4 v = (gr < GN) ? ((const float4*)A)[(size_t)gr * 32 + c4]
                         : make_float4(0.f, 0.f, 0.f, 0.f);
    int c = c4 * 4;
    v.x = fmaxf(fmaf(v.x, sc[c],     sh[c]),     0.f);
    v.y = fmaxf(fmaf(v.y, sc[c + 1], sh[c + 1]), 0.f);
    v.z = fmaxf(fmaf(v.z, sc[c + 2], sh[c + 2]), 0.f);
    v.w = fmaxf(fmaf(v.w, sc[c + 3], sh[c + 3]), 0.f);
    ((float4*)alds)[i] = v;
  }
  __syncthreads();
  int j0 = (t & 15) * 4;
  int r0 = (t >> 4) * 2;
  float4 acc0 = {0, 0, 0, 0}, acc1 = {0, 0, 0, 0};
  #pragma unroll 8
  for (int k = 0; k < 128; ++k) {
    float4 w = *(const float4*)&wlds[k * 64 + j0];
    float a0 = alds[r0 * 128 + k];
    float a1 = alds[(r0 + 1) * 128 + k];
    acc0.x += a0 * w.x; acc0.y += a0 * w.y; acc0.z += a0 * w.z; acc0.w += a0 * w.w;
    acc1.x += a1 * w.x; acc1.y += a1 * w.y; acc1.z += a1 * w.z; acc1.w += a1 * w.w;
  }
  int gr0 = row0 + r0;
  if (gr0 < GN)     *(float4*)&C[(size_t)gr0 * 64 + j0] = acc0;
  if (gr0 + 1 < GN) *(float4*)&C[(size_t)(gr0 + 1) * 64 + j0] = acc1;
}

// wave-per-node gather: hidden[d] = dinv[d]*(dinv[d]*h1[d] + sum_{s->d} dinv[s]*h1[s]) + b1
__global__ __launch_bounds__(256) void agg1_kernel(const float* __restrict__ h1,
    const int* __restrict__ row, const int* __restrict__ srcs,
    const float* __restrict__ dinv, const float* __restrict__ b1,
    float* __restrict__ hidden) {
  int wave = (blockIdx.x * 256 + threadIdx.x) >> 6;
  int lane = threadIdx.x & 63;
  if (wave >= GN) return;
  int d = wave;
  float di = dinv[d];
  float2 acc = ((const float2*)(h1 + (size_t)d * 128))[lane];
  acc.x *= di; acc.y *= di;                       // self-loop: dinv[d]^2 after final *di
  int e0 = row[d], e1 = row[d + 1];
  for (int i = e0; i < e1; ++i) {
    int s = srcs[i];
    float w = dinv[s];
    float2 v = ((const float2*)(h1 + (size_t)s * 128))[lane];
    acc.x += w * v.x; acc.y += w * v.y;
  }
  float2 b = ((const float2*)b1)[lane];
  float2 o; o.x = acc.x * di + b.x; o.y = acc.y * di + b.y;
  ((float2*)(hidden + (size_t)d * 128))[lane] = o;
}

__global__ __launch_bounds__(256) void agg2_kernel(const float* __restrict__ h2,
    const int* __restrict__ row, const int* __restrict__ srcs,
    const float* __restrict__ dinv, const float* __restrict__ b2,
    float* __restrict__ out) {
  int wave = (blockIdx.x * 256 + threadIdx.x) >> 6;
  int lane = threadIdx.x & 63;
  if (wave >= GN) return;
  int d = wave;
  float di = dinv[d];
  float acc = h2[(size_t)d * 64 + lane] * di;
  int e0 = row[d], e1 = row[d + 1];
  for (int i = e0; i < e1; ++i) {
    int s = srcs[i];
    acc += dinv[s] * h2[(size_t)s * 64 + lane];
  }
  out[(size_t)d * 64 + lane] = acc * di + b2[lane];
}

__global__ __launch_bounds__(256) void bn_stats_kernel(const float* __restrict__ h,
    float* __restrict__ sum, float* __restrict__ sumsq) {
  int gt = blockIdx.x * 256 + threadIdx.x;   // 65536 threads = 512 row streams x 128 cols
  int c = gt & 127;
  int r = gt >> 7;
  float s = 0.f, ss = 0.f;
  for (; r < GN; r += 512) { float v = h[(size_t)r * 128 + c]; s += v; ss += v * v; }
  atomicAdd(&sum[c], s);
  atomicAdd(&sumsq[c], ss);
}

__global__ __launch_bounds__(128) void bn_final_kernel(const float* __restrict__ sum,
    const float* __restrict__ sumsq, const float* __restrict__ gamma,
    const float* __restrict__ beta, float* __restrict__ scale, float* __restrict__ shift) {
  int c = threadIdx.x;
  float mean = sum[c] * (1.0f / GN);
  float var = sumsq[c] * (1.0f / GN) - mean * mean;
  float istd = rsqrtf(var + 1e-5f);
  float g = gamma[c] * istd;
  scale[c] = g;
  shift[c] = beta[c] - mean * g;
}

extern "C" void kernel_launch(void* const* d_in, const int* in_sizes, int n_in,
                              void* d_out, int out_size, void* d_ws, size_t ws_size,
                              hipStream_t stream) {
  const float* x     = (const float*)d_in[0];
  const int*   e1    = (const int*)d_in[1];
  const int*   e2    = (const int*)d_in[2];
  const float* W1    = (const float*)d_in[3];
  const float* b1    = (const float*)d_in[4];
  const float* gamma = (const float*)d_in[5];
  const float* beta  = (const float*)d_in[6];
  const float* W2    = (const float*)d_in[7];
  const float* b2    = (const float*)d_in[8];

  float* out    = (float*)d_out;               // [N,64]
  float* hidden = out + (size_t)GN * OUTC;     // [N,128] second tuple element

  float* ws    = (float*)d_ws;
  float* h1    = ws + OFF_H1;
  float* h2    = ws + OFF_H2;
  float* dinv1 = ws + OFF_DINV1;
  float* dinv2 = ws + OFF_DINV2;
  int*   row1  = (int*)(ws + OFF_ROW1);
  int*   row2  = (int*)(ws + OFF_ROW2);
  int*   cur1  = (int*)(ws + OFF_CUR1);
  int*   cur2  = (int*)(ws + OFF_CUR2);
  int*   cnt1  = (int*)(ws + OFF_CNT1);
  int*   cnt2  = (int*)(ws + OFF_CNT2);
  float* bnbuf = ws + OFF_BN;
  int*   src1  = (int*)(ws + OFF_SRC1);
  int*   src2  = (int*)(ws + OFF_SRC2);
  int*   bsum  = (int*)(ws + OFF_BSUM);
  int*   bofs  = (int*)(ws + OFF_BOFS);
  int*   bcur1 = (int*)(ws + OFF_BCUR1);
  int*   bcur2 = (int*)(ws + OFF_BCUR2);
  // pair buffers alias h2: consumed (pair_fill) before gemm2 produces h2 (same stream)
  int2*  pair1 = (int2*)h2;
  int2*  pair2 = pair1 + GE;

  // zero cnt1, cnt2, bn sums (contiguous region)
  hipMemsetAsync(ws + OFF_CNT1, 0, (size_t)(2 * GN + 512) * sizeof(float), stream);

  count_kernel<<<(GE + 255) / 256, 256, 0, stream>>>(e1, e2, cnt1, cnt2);
  scanA_kernel<<<2 * NB, 256, 0, stream>>>(cnt1, cnt2, bsum);
  scanB_kernel<<<1, 256, 0, stream>>>(bsum, bofs, row1, row2);
  scanC_kernel<<<2 * NB, 256, 0, stream>>>(cnt1, cnt2, bofs,
                                           row1, cur1, dinv1, row2, cur2, dinv2,
                                           bcur1, bcur2);
  pair_scatter_kernel<<<(GE + 255) / 256, 256, 0, stream>>>(e1, e2, bcur1, bcur2,
                                                            pair1, pair2);
  pair_fill_kernel<<<(GE + 255) / 256, 256, 0, stream>>>(pair1, pair2, cur1, cur2,
                                                         src1, src2);

  gemm1_kernel<<<dim3((GN + 31) / 32, 2), 256, 0, stream>>>(x, W1, h1);
  agg1_kernel<<<(GN * 64 + 255) / 256, 256, 0, stream>>>(h1, row1, src1, dinv1, b1, hidden);

  bn_stats_kernel<<<256, 256, 0, stream>>>(hidden, bnbuf, bnbuf + 128);
  bn_final_kernel<<<1, 128, 0, stream>>>(bnbuf, bnbuf + 128, gamma, beta,
                                         bnbuf + 256, bnbuf + 384);

  gemm2_kernel<<<dim3((GN + 31) / 32, 1), 256, 0, stream>>>(hidden, W2,
                                                            bnbuf + 256, bnbuf + 384, h2);
  agg2_kernel<<<(GN * 64 + 255) / 256, 256, 0, stream>>>(h2, row2, src2, dinv2, b2, out);
}

// Round 4
// 505.894 us; speedup vs baseline: 1.3053x; 1.3053x over previous
//
#include <hip/hip_runtime.h>

#define GN 50000      // nodes
#define GE 800000     // edges per graph
#define HID 128
#define OUTC 64
#define NB 196        // scan blocks per graph: ceil(50000/256)
#define NREG (GN / 8) // 6250 nodes per XCD-owned region

// workspace layout (float element offsets)
#define OFF_H1    0            // 6,400,000 f  (x@W1)
#define OFF_H2    6400000      // 3,200,000 f  (relu(bn(hidden))@W2)
#define OFF_DINV1 9600000      // 50,000
#define OFF_DINV2 9650000      // 50,000
#define OFF_ROW1  9700000      // 50,001 int
#define OFF_ROW2  9750004      // 50,001 int
#define OFF_CUR1  9800008      // 50,000 int
#define OFF_CUR2  9850008      // 50,000 int
#define OFF_CNT1  9900008      // 50,000 int   -- memset region start
#define OFF_CNT2  9950008      // 50,000 int
#define OFF_BN    10000008     // 512 f: sum@0 sumsq@128 scale@256 shift@384
#define OFF_SRC1  10000520     // 800,000 int
#define OFF_SRC2  10800520     // 800,000 int
#define OFF_BSUM  11600520     // 2*NB int  (per-block sums, both graphs)
#define OFF_BOFS  11601032     // 2*NB int  (scanned block offsets)

__global__ __launch_bounds__(256) void count_kernel(const int* __restrict__ e1,
    const int* __restrict__ e2, int* __restrict__ cnt1, int* __restrict__ cnt2) {
  int i = blockIdx.x * 256 + threadIdx.x;
  if (i < GE) {
    atomicAdd(&cnt1[e1[GE + i]], 1);   // dst of graph 1
    atomicAdd(&cnt2[e2[GE + i]], 1);   // dst of graph 2
  }
}

// stage A: per-block sums of cnt. grid = 2*NB blocks; blockIdx.x >= NB -> graph 2
__global__ __launch_bounds__(256) void scanA_kernel(const int* __restrict__ cnt1,
    const int* __restrict__ cnt2, int* __restrict__ bsum) {
  __shared__ int lds[256];
  int b = blockIdx.x;
  int g = (b >= NB) ? 1 : 0;
  int lb = b - g * NB;
  const int* cnt = g ? cnt2 : cnt1;
  int idx = lb * 256 + threadIdx.x;
  int v = (idx < GN) ? cnt[idx] : 0;
  lds[threadIdx.x] = v;
  __syncthreads();
  for (int off = 128; off > 0; off >>= 1) {
    if (threadIdx.x < off) lds[threadIdx.x] += lds[threadIdx.x + off];
    __syncthreads();
  }
  if (threadIdx.x == 0) bsum[b] = lds[0];
}

// stage B: 1 block, exclusive-scan the NB block-sums for each graph; write totals to row[GN]
__global__ __launch_bounds__(256) void scanB_kernel(const int* __restrict__ bsum,
    int* __restrict__ bofs, int* __restrict__ row1, int* __restrict__ row2) {
  __shared__ int lds[256];
  int t = threadIdx.x;
  for (int g = 0; g < 2; ++g) {
    int v = (t < NB) ? bsum[g * NB + t] : 0;
    int orig = v;
    lds[t] = v;
    __syncthreads();
    for (int off = 1; off < 256; off <<= 1) {
      int u = (t >= off) ? lds[t - off] : 0;
      __syncthreads();
      lds[t] += u;
      __syncthreads();
    }
    if (t < NB) bofs[g * NB + t] = lds[t] - orig;   // exclusive
    if (t == NB - 1) { if (g) row2[GN] = lds[t]; else row1[GN] = lds[t]; }
    __syncthreads();
  }
}

// stage C: per-block local exclusive scan + block offset -> row/cur; dinv = rsqrt(1+cnt)
__global__ __launch_bounds__(256) void scanC_kernel(const int* __restrict__ cnt1,
    const int* __restrict__ cnt2, const int* __restrict__ bofs,
    int* __restrict__ row1, int* __restrict__ cur1, float* __restrict__ dinv1,
    int* __restrict__ row2, int* __restrict__ cur2, float* __restrict__ dinv2) {
  __shared__ int lds[256];
  int b = blockIdx.x;
  int g = (b >= NB) ? 1 : 0;
  int lb = b - g * NB;
  const int* cnt = g ? cnt2 : cnt1;
  int* row = g ? row2 : row1;
  int* cur = g ? cur2 : cur1;
  float* dinv = g ? dinv2 : dinv1;
  int t = threadIdx.x;
  int idx = lb * 256 + t;
  int v = (idx < GN) ? cnt[idx] : 0;
  lds[t] = v;
  __syncthreads();
  for (int off = 1; off < 256; off <<= 1) {
    int u = (t >= off) ? lds[t - off] : 0;
    __syncthreads();
    lds[t] += u;
    __syncthreads();
  }
  if (idx < GN) {
    int e = bofs[b] + lds[t] - v;   // exclusive prefix
    row[idx] = e;
    cur[idx] = e;
    dinv[idx] = rsqrtf(1.0f + (float)v);
  }
}

// XCD-local CSR fill: group k = blockIdx.x & 7 (round-robin XCD heuristic) scans ALL
// edges, keeps only dst in [k*NREG, (k+1)*NREG) -> all writes to a CSR region come
// from one XCD -> lines assemble in its L2 (compact writeback). Correct regardless
// of the block->XCD mapping; only locality depends on it.
__global__ __launch_bounds__(256) void fill_xcd_kernel(const int* __restrict__ e1,
    const int* __restrict__ e2, int* __restrict__ cur1, int* __restrict__ cur2,
    int* __restrict__ src1, int* __restrict__ src2) {
  int g = blockIdx.y;
  const int* e = g ? e2 : e1;
  int* cur = g ? cur2 : cur1;
  int* src = g ? src2 : src1;
  int lo = (blockIdx.x & 7) * NREG;
  int start = (blockIdx.x >> 3) * 256 + threadIdx.x;   // 128 blocks/group x 256 threads
  for (int i = start; i < GE; i += 128 * 256) {
    int d = e[GE + i];
    if ((unsigned)(d - lo) < (unsigned)NREG) {
      int p = atomicAdd(&cur[d], 1);
      src[p] = e[i];
    }
  }
}

// C[M,128] = A[M,128] @ B[128,128]; block tile 32 rows x 64 cols (blockIdx.y selects col half)
__global__ __launch_bounds__(256) void gemm1_kernel(const float* __restrict__ A,
    const float* __restrict__ B, float* __restrict__ C) {
  __shared__ __align__(16) float wlds[128 * 64];
  __shared__ __align__(16) float alds[32 * 128];
  int t = threadIdx.x;
  int row0 = blockIdx.x * 32;
  int cb = blockIdx.y * 64;
  for (int i = t; i < 128 * 16; i += 256) {        // W tile: 128 rows x 16 float4
    int k = i >> 4, c4 = i & 15;
    ((float4*)wlds)[i] = ((const float4*)B)[k * 32 + (cb >> 2) + c4];
  }
  for (int i = t; i < 1024; i += 256) {            // A tile: 32 rows x 32 float4
    int r = i >> 5, c4 = i & 31;
    int gr = row0 + r;
    ((float4*)alds)[i] = (gr < GN) ? ((const float4*)A)[(size_t)gr * 32 + c4]
                                   : make_float4(0.f, 0.f, 0.f, 0.f);
  }
  __syncthreads();
  int j0 = (t & 15) * 4;
  int r0 = (t >> 4) * 2;
  float4 acc0 = {0, 0, 0, 0}, acc1 = {0, 0, 0, 0};
  #pragma unroll 8
  for (int k = 0; k < 128; ++k) {
    float4 w = *(const float4*)&wlds[k * 64 + j0];
    float a0 = alds[r0 * 128 + k];
    float a1 = alds[(r0 + 1) * 128 + k];
    acc0.x += a0 * w.x; acc0.y += a0 * w.y; acc0.z += a0 * w.z; acc0.w += a0 * w.w;
    acc1.x += a1 * w.x; acc1.y += a1 * w.y; acc1.z += a1 * w.z; acc1.w += a1 * w.w;
  }
  int gr0 = row0 + r0;
  if (gr0 < GN)     *(float4*)&C[(size_t)gr0 * 128 + cb + j0] = acc0;
  if (gr0 + 1 < GN) *(float4*)&C[(size_t)(gr0 + 1) * 128 + cb + j0] = acc1;
}

// C[M,64] = relu(bn(A[M,128])) @ B[128,64]
__global__ __launch_bounds__(256) void gemm2_kernel(const float* __restrict__ A,
    const float* __restrict__ B, const float* __restrict__ scale,
    const float* __restrict__ shift, float* __restrict__ C) {
  __shared__ __align__(16) float wlds[128 * 64];
  __shared__ __align__(16) float alds[32 * 128];
  __shared__ float sc[128], sh[128];
  int t = threadIdx.x;
  if (t < 128) { sc[t] = scale[t]; sh[t] = shift[t]; }
  int row0 = blockIdx.x * 32;
  for (int i = t; i < 128 * 16; i += 256)
    ((float4*)wlds)[i] = ((const float4*)B)[i];
  __syncthreads();   // sc/sh ready before prologue
  for (int i = t; i < 1024; i += 256) {
    int r = i >> 5, c4 = i & 31;
    int gr = row0 + r;
    float4 v = (gr < GN) ? ((const float4*)A)[(size_t)gr * 32 + c4]
                         : make_float4(0.f, 0.f, 0.f, 0.f);
    int c = c4 * 4;
    v.x = fmaxf(fmaf(v.x, sc[c],     sh[c]),     0.f);
    v.y = fmaxf(fmaf(v.y, sc[c + 1], sh[c + 1]), 0.f);
    v.z = fmaxf(fmaf(v.z, sc[c + 2], sh[c + 2]), 0.f);
    v.w = fmaxf(fmaf(v.w, sc[c + 3], sh[c + 3]), 0.f);
    ((float4*)alds)[i] = v;
  }
  __syncthreads();
  int j0 = (t & 15) * 4;
  int r0 = (t >> 4) * 2;
  float4 acc0 = {0, 0, 0, 0}, acc1 = {0, 0, 0, 0};
  #pragma unroll 8
  for (int k = 0; k < 128; ++k) {
    float4 w = *(const float4*)&wlds[k * 64 + j0];
    float a0 = alds[r0 * 128 + k];
    float a1 = alds[(r0 + 1) * 128 + k];
    acc0.x += a0 * w.x; acc0.y += a0 * w.y; acc0.z += a0 * w.z; acc0.w += a0 * w.w;
    acc1.x += a1 * w.x; acc1.y += a1 * w.y; acc1.z += a1 * w.z; acc1.w += a1 * w.w;
  }
  int gr0 = row0 + r0;
  if (gr0 < GN)     *(float4*)&C[(size_t)gr0 * 64 + j0] = acc0;
  if (gr0 + 1 < GN) *(float4*)&C[(size_t)(gr0 + 1) * 64 + j0] = acc1;
}

// wave-per-node gather: hidden[d] = dinv[d]*(dinv[d]*h1[d] + sum_{s->d} dinv[s]*h1[s]) + b1
__global__ __launch_bounds__(256) void agg1_kernel(const float* __restrict__ h1,
    const int* __restrict__ row, const int* __restrict__ srcs,
    const float* __restrict__ dinv, const float* __restrict__ b1,
    float* __restrict__ hidden) {
  int wave = (blockIdx.x * 256 + threadIdx.x) >> 6;
  int lane = threadIdx.x & 63;
  if (wave >= GN) return;
  int d = wave;
  float di = dinv[d];
  float2 acc = ((const float2*)(h1 + (size_t)d * 128))[lane];
  acc.x *= di; acc.y *= di;                       // self-loop: dinv[d]^2 after final *di
  int e0 = row[d], e1 = row[d + 1];
  for (int i = e0; i < e1; ++i) {
    int s = srcs[i];
    float w = dinv[s];
    float2 v = ((const float2*)(h1 + (size_t)s * 128))[lane];
    acc.x += w * v.x; acc.y += w * v.y;
  }
  float2 b = ((const float2*)b1)[lane];
  float2 o; o.x = acc.x * di + b.x; o.y = acc.y * di + b.y;
  ((float2*)(hidden + (size_t)d * 128))[lane] = o;
}

__global__ __launch_bounds__(256) void agg2_kernel(const float* __restrict__ h2,
    const int* __restrict__ row, const int* __restrict__ srcs,
    const float* __restrict__ dinv, const float* __restrict__ b2,
    float* __restrict__ out) {
  int wave = (blockIdx.x * 256 + threadIdx.x) >> 6;
  int lane = threadIdx.x & 63;
  if (wave >= GN) return;
  int d = wave;
  float di = dinv[d];
  float acc = h2[(size_t)d * 64 + lane] * di;
  int e0 = row[d], e1 = row[d + 1];
  for (int i = e0; i < e1; ++i) {
    int s = srcs[i];
    acc += dinv[s] * h2[(size_t)s * 64 + lane];
  }
  out[(size_t)d * 64 + lane] = acc * di + b2[lane];
}

__global__ __launch_bounds__(256) void bn_stats_kernel(const float* __restrict__ h,
    float* __restrict__ sum, float* __restrict__ sumsq) {
  int gt = blockIdx.x * 256 + threadIdx.x;   // 65536 threads = 512 row streams x 128 cols
  int c = gt & 127;
  int r = gt >> 7;
  float s = 0.f, ss = 0.f;
  for (; r < GN; r += 512) { float v = h[(size_t)r * 128 + c]; s += v; ss += v * v; }
  atomicAdd(&sum[c], s);
  atomicAdd(&sumsq[c], ss);
}

__global__ __launch_bounds__(128) void bn_final_kernel(const float* __restrict__ sum,
    const float* __restrict__ sumsq, const float* __restrict__ gamma,
    const float* __restrict__ beta, float* __restrict__ scale, float* __restrict__ shift) {
  int c = threadIdx.x;
  float mean = sum[c] * (1.0f / GN);
  float var = sumsq[c] * (1.0f / GN) - mean * mean;
  float istd = rsqrtf(var + 1e-5f);
  float g = gamma[c] * istd;
  scale[c] = g;
  shift[c] = beta[c] - mean * g;
}

extern "C" void kernel_launch(void* const* d_in, const int* in_sizes, int n_in,
                              void* d_out, int out_size, void* d_ws, size_t ws_size,
                              hipStream_t stream) {
  const float* x     = (const float*)d_in[0];
  const int*   e1    = (const int*)d_in[1];
  const int*   e2    = (const int*)d_in[2];
  const float* W1    = (const float*)d_in[3];
  const float* b1    = (const float*)d_in[4];
  const float* gamma = (const float*)d_in[5];
  const float* beta  = (const float*)d_in[6];
  const float* W2    = (const float*)d_in[7];
  const float* b2    = (const float*)d_in[8];

  float* out    = (float*)d_out;               // [N,64]
  float* hidden = out + (size_t)GN * OUTC;     // [N,128] second tuple element

  float* ws    = (float*)d_ws;
  float* h1    = ws + OFF_H1;
  float* h2    = ws + OFF_H2;
  float* dinv1 = ws + OFF_DINV1;
  float* dinv2 = ws + OFF_DINV2;
  int*   row1  = (int*)(ws + OFF_ROW1);
  int*   row2  = (int*)(ws + OFF_ROW2);
  int*   cur1  = (int*)(ws + OFF_CUR1);
  int*   cur2  = (int*)(ws + OFF_CUR2);
  int*   cnt1  = (int*)(ws + OFF_CNT1);
  int*   cnt2  = (int*)(ws + OFF_CNT2);
  float* bnbuf = ws + OFF_BN;
  int*   src1  = (int*)(ws + OFF_SRC1);
  int*   src2  = (int*)(ws + OFF_SRC2);
  int*   bsum  = (int*)(ws + OFF_BSUM);
  int*   bofs  = (int*)(ws + OFF_BOFS);

  // zero cnt1, cnt2, bn sums (contiguous region)
  hipMemsetAsync(ws + OFF_CNT1, 0, (size_t)(2 * GN + 512) * sizeof(float), stream);

  count_kernel<<<(GE + 255) / 256, 256, 0, stream>>>(e1, e2, cnt1, cnt2);
  scanA_kernel<<<2 * NB, 256, 0, stream>>>(cnt1, cnt2, bsum);
  scanB_kernel<<<1, 256, 0, stream>>>(bsum, bofs, row1, row2);
  scanC_kernel<<<2 * NB, 256, 0, stream>>>(cnt1, cnt2, bofs,
                                           row1, cur1, dinv1, row2, cur2, dinv2);
  fill_xcd_kernel<<<dim3(1024, 2), 256, 0, stream>>>(e1, e2, cur1, cur2, src1, src2);

  gemm1_kernel<<<dim3((GN + 31) / 32, 2), 256, 0, stream>>>(x, W1, h1);
  agg1_kernel<<<(GN * 64 + 255) / 256, 256, 0, stream>>>(h1, row1, src1, dinv1, b1, hidden);

  bn_stats_kernel<<<256, 256, 0, stream>>>(hidden, bnbuf, bnbuf + 128);
  bn_final_kernel<<<1, 128, 0, stream>>>(bnbuf, bnbuf + 128, gamma, beta,
                                         bnbuf + 256, bnbuf + 384);

  gemm2_kernel<<<dim3((GN + 31) / 32, 1), 256, 0, stream>>>(hidden, W2,
                                                            bnbuf + 256, bnbuf + 384, h2);
  agg2_kernel<<<(GN * 64 + 255) / 256, 256, 0, stream>>>(h2, row2, src2, dinv2, b2, out);
}

// Round 5
// 437.293 us; speedup vs baseline: 1.5100x; 1.1569x over previous
//
#include <hip/hip_runtime.h>

#define GN 50000      // nodes
#define GE 800000     // edges per graph
#define HID 128
#define OUTC 64
#define NB 196        // scan blocks per graph: ceil(50000/256)
#define NREG (GN / 8) // 6250 nodes per XCD-owned region

// workspace layout (float element offsets)
#define OFF_H1    0            // 6,400,000 f  (x@W1)
#define OFF_H2    6400000      // 3,200,000 f  (relu(bn(hidden))@W2)
#define OFF_DINV1 9600000      // 50,000
#define OFF_DINV2 9650000      // 50,000
#define OFF_ROW1  9700000      // 50,001 int
#define OFF_ROW2  9750004      // 50,001 int
#define OFF_CUR1  9800008      // 50,000 int
#define OFF_CUR2  9850008      // 50,000 int
#define OFF_CNT1  9900008      // 50,000 int   -- memset region start
#define OFF_CNT2  9950008      // 50,000 int
#define OFF_BN    10000008     // 512 f: sum@0 sumsq@128 scale@256 shift@384
#define OFF_SRC1  10000520     // 800,000 int
#define OFF_SRC2  10800520     // 800,000 int
#define OFF_BSUM  11600520     // 2*NB int  (per-block sums, both graphs)
#define OFF_BOFS  11601032     // 2*NB int  (scanned block offsets)

__global__ __launch_bounds__(256) void count_kernel(const int* __restrict__ e1,
    const int* __restrict__ e2, int* __restrict__ cnt1, int* __restrict__ cnt2) {
  int i = blockIdx.x * 256 + threadIdx.x;
  if (i < GE) {
    atomicAdd(&cnt1[e1[GE + i]], 1);   // dst of graph 1
    atomicAdd(&cnt2[e2[GE + i]], 1);   // dst of graph 2
  }
}

// stage A: per-block sums of cnt. grid = 2*NB blocks; blockIdx.x >= NB -> graph 2
__global__ __launch_bounds__(256) void scanA_kernel(const int* __restrict__ cnt1,
    const int* __restrict__ cnt2, int* __restrict__ bsum) {
  __shared__ int lds[256];
  int b = blockIdx.x;
  int g = (b >= NB) ? 1 : 0;
  int lb = b - g * NB;
  const int* cnt = g ? cnt2 : cnt1;
  int idx = lb * 256 + threadIdx.x;
  int v = (idx < GN) ? cnt[idx] : 0;
  lds[threadIdx.x] = v;
  __syncthreads();
  for (int off = 128; off > 0; off >>= 1) {
    if (threadIdx.x < off) lds[threadIdx.x] += lds[threadIdx.x + off];
    __syncthreads();
  }
  if (threadIdx.x == 0) bsum[b] = lds[0];
}

// stage B: 1 block, exclusive-scan the NB block-sums for each graph; write totals to row[GN]
__global__ __launch_bounds__(256) void scanB_kernel(const int* __restrict__ bsum,
    int* __restrict__ bofs, int* __restrict__ row1, int* __restrict__ row2) {
  __shared__ int lds[256];
  int t = threadIdx.x;
  for (int g = 0; g < 2; ++g) {
    int v = (t < NB) ? bsum[g * NB + t] : 0;
    int orig = v;
    lds[t] = v;
    __syncthreads();
    for (int off = 1; off < 256; off <<= 1) {
      int u = (t >= off) ? lds[t - off] : 0;
      __syncthreads();
      lds[t] += u;
      __syncthreads();
    }
    if (t < NB) bofs[g * NB + t] = lds[t] - orig;   // exclusive
    if (t == NB - 1) { if (g) row2[GN] = lds[t]; else row1[GN] = lds[t]; }
    __syncthreads();
  }
}

// stage C: per-block local exclusive scan + block offset -> row/cur; dinv = rsqrt(1+cnt)
__global__ __launch_bounds__(256) void scanC_kernel(const int* __restrict__ cnt1,
    const int* __restrict__ cnt2, const int* __restrict__ bofs,
    int* __restrict__ row1, int* __restrict__ cur1, float* __restrict__ dinv1,
    int* __restrict__ row2, int* __restrict__ cur2, float* __restrict__ dinv2) {
  __shared__ int lds[256];
  int b = blockIdx.x;
  int g = (b >= NB) ? 1 : 0;
  int lb = b - g * NB;
  const int* cnt = g ? cnt2 : cnt1;
  int* row = g ? row2 : row1;
  int* cur = g ? cur2 : cur1;
  float* dinv = g ? dinv2 : dinv1;
  int t = threadIdx.x;
  int idx = lb * 256 + t;
  int v = (idx < GN) ? cnt[idx] : 0;
  lds[t] = v;
  __syncthreads();
  for (int off = 1; off < 256; off <<= 1) {
    int u = (t >= off) ? lds[t - off] : 0;
    __syncthreads();
    lds[t] += u;
    __syncthreads();
  }
  if (idx < GN) {
    int e = bofs[b] + lds[t] - v;   // exclusive prefix
    row[idx] = e;
    cur[idx] = e;
    dinv[idx] = rsqrtf(1.0f + (float)v);
  }
}

// XCD-local CSR fill: group k = blockIdx.x & 7 scans ALL edges, keeps dst in its region
__global__ __launch_bounds__(256) void fill_xcd_kernel(const int* __restrict__ e1,
    const int* __restrict__ e2, int* __restrict__ cur1, int* __restrict__ cur2,
    int* __restrict__ src1, int* __restrict__ src2) {
  int g = blockIdx.y;
  const int* e = g ? e2 : e1;
  int* cur = g ? cur2 : cur1;
  int* src = g ? src2 : src1;
  int lo = (blockIdx.x & 7) * NREG;
  int start = (blockIdx.x >> 3) * 256 + threadIdx.x;   // 128 blocks/group x 256 threads
  for (int i = start; i < GE; i += 128 * 256) {
    int d = e[GE + i];
    if ((unsigned)(d - lo) < (unsigned)NREG) {
      int p = atomicAdd(&cur[d], 1);
      src[p] = e[i];
    }
  }
}

// C[M,128] = A[M,128] @ B[128,128]; block tile 32 rows x 64 cols (blockIdx.y selects col half)
__global__ __launch_bounds__(256) void gemm1_kernel(const float* __restrict__ A,
    const float* __restrict__ B, float* __restrict__ C) {
  __shared__ __align__(16) float wlds[128 * 64];
  __shared__ __align__(16) float alds[32 * 128];
  int t = threadIdx.x;
  int row0 = blockIdx.x * 32;
  int cb = blockIdx.y * 64;
  for (int i = t; i < 128 * 16; i += 256) {        // W tile: 128 rows x 16 float4
    int k = i >> 4, c4 = i & 15;
    ((float4*)wlds)[i] = ((const float4*)B)[k * 32 + (cb >> 2) + c4];
  }
  for (int i = t; i < 1024; i += 256) {            // A tile: 32 rows x 32 float4
    int r = i >> 5, c4 = i & 31;
    int gr = row0 + r;
    ((float4*)alds)[i] = (gr < GN) ? ((const float4*)A)[(size_t)gr * 32 + c4]
                                   : make_float4(0.f, 0.f, 0.f, 0.f);
  }
  __syncthreads();
  int j0 = (t & 15) * 4;
  int r0 = (t >> 4) * 2;
  float4 acc0 = {0, 0, 0, 0}, acc1 = {0, 0, 0, 0};
  #pragma unroll 8
  for (int k = 0; k < 128; ++k) {
    float4 w = *(const float4*)&wlds[k * 64 + j0];
    float a0 = alds[r0 * 128 + k];
    float a1 = alds[(r0 + 1) * 128 + k];
    acc0.x += a0 * w.x; acc0.y += a0 * w.y; acc0.z += a0 * w.z; acc0.w += a0 * w.w;
    acc1.x += a1 * w.x; acc1.y += a1 * w.y; acc1.z += a1 * w.z; acc1.w += a1 * w.w;
  }
  int gr0 = row0 + r0;
  if (gr0 < GN)     *(float4*)&C[(size_t)gr0 * 128 + cb + j0] = acc0;
  if (gr0 + 1 < GN) *(float4*)&C[(size_t)(gr0 + 1) * 128 + cb + j0] = acc1;
}

// C[M,64] = relu(bn(A[M,128])) @ B[128,64]
__global__ __launch_bounds__(256) void gemm2_kernel(const float* __restrict__ A,
    const float* __restrict__ B, const float* __restrict__ scale,
    const float* __restrict__ shift, float* __restrict__ C) {
  __shared__ __align__(16) float wlds[128 * 64];
  __shared__ __align__(16) float alds[32 * 128];
  __shared__ float sc[128], sh[128];
  int t = threadIdx.x;
  if (t < 128) { sc[t] = scale[t]; sh[t] = shift[t]; }
  int row0 = blockIdx.x * 32;
  for (int i = t; i < 128 * 16; i += 256)
    ((float4*)wlds)[i] = ((const float4*)B)[i];
  __syncthreads();   // sc/sh ready before prologue
  for (int i = t; i < 1024; i += 256) {
    int r = i >> 5, c4 = i & 31;
    int gr = row0 + r;
    float4 v = (gr < GN) ? ((const float4*)A)[(size_t)gr * 32 + c4]
                         : make_float4(0.f, 0.f, 0.f, 0.f);
    int c = c4 * 4;
    v.x = fmaxf(fmaf(v.x, sc[c],     sh[c]),     0.f);
    v.y = fmaxf(fmaf(v.y, sc[c + 1], sh[c + 1]), 0.f);
    v.z = fmaxf(fmaf(v.z, sc[c + 2], sh[c + 2]), 0.f);
    v.w = fmaxf(fmaf(v.w, sc[c + 3], sh[c + 3]), 0.f);
    ((float4*)alds)[i] = v;
  }
  __syncthreads();
  int j0 = (t & 15) * 4;
  int r0 = (t >> 4) * 2;
  float4 acc0 = {0, 0, 0, 0}, acc1 = {0, 0, 0, 0};
  #pragma unroll 8
  for (int k = 0; k < 128; ++k) {
    float4 w = *(const float4*)&wlds[k * 64 + j0];
    float a0 = alds[r0 * 128 + k];
    float a1 = alds[(r0 + 1) * 128 + k];
    acc0.x += a0 * w.x; acc0.y += a0 * w.y; acc0.z += a0 * w.z; acc0.w += a0 * w.w;
    acc1.x += a1 * w.x; acc1.y += a1 * w.y; acc1.z += a1 * w.z; acc1.w += a1 * w.w;
  }
  int gr0 = row0 + r0;
  if (gr0 < GN)     *(float4*)&C[(size_t)gr0 * 64 + j0] = acc0;
  if (gr0 + 1 < GN) *(float4*)&C[(size_t)(gr0 + 1) * 64 + j0] = acc1;
}

// wave-per-node gather, 4x unrolled for MLP:
// hidden[d] = dinv[d]*(dinv[d]*h1[d] + sum_{s->d} dinv[s]*h1[s]) + b1
__global__ __launch_bounds__(256) void agg1_kernel(const float* __restrict__ h1,
    const int* __restrict__ row, const int* __restrict__ srcs,
    const float* __restrict__ dinv, const float* __restrict__ b1,
    float* __restrict__ hidden) {
  int wave = (blockIdx.x * 256 + threadIdx.x) >> 6;
  int lane = threadIdx.x & 63;
  if (wave >= GN) return;
  int d = wave;
  float di = dinv[d];
  float2 acc = ((const float2*)(h1 + (size_t)d * 128))[lane];
  acc.x *= di; acc.y *= di;                       // self-loop: dinv[d]^2 after final *di
  int e0 = row[d], e1 = row[d + 1];
  int i = e0;
  for (; i + 4 <= e1; i += 4) {
    int s0 = srcs[i], s1 = srcs[i + 1], s2 = srcs[i + 2], s3 = srcs[i + 3];
    float w0 = dinv[s0], w1 = dinv[s1], w2 = dinv[s2], w3 = dinv[s3];
    float2 v0 = ((const float2*)(h1 + (size_t)s0 * 128))[lane];
    float2 v1 = ((const float2*)(h1 + (size_t)s1 * 128))[lane];
    float2 v2 = ((const float2*)(h1 + (size_t)s2 * 128))[lane];
    float2 v3 = ((const float2*)(h1 + (size_t)s3 * 128))[lane];
    acc.x += w0 * v0.x; acc.y += w0 * v0.y;
    acc.x += w1 * v1.x; acc.y += w1 * v1.y;
    acc.x += w2 * v2.x; acc.y += w2 * v2.y;
    acc.x += w3 * v3.x; acc.y += w3 * v3.y;
  }
  for (; i < e1; ++i) {
    int s = srcs[i];
    float w = dinv[s];
    float2 v = ((const float2*)(h1 + (size_t)s * 128))[lane];
    acc.x += w * v.x; acc.y += w * v.y;
  }
  float2 b = ((const float2*)b1)[lane];
  float2 o; o.x = acc.x * di + b.x; o.y = acc.y * di + b.y;
  ((float2*)(hidden + (size_t)d * 128))[lane] = o;
}

__global__ __launch_bounds__(256) void agg2_kernel(const float* __restrict__ h2,
    const int* __restrict__ row, const int* __restrict__ srcs,
    const float* __restrict__ dinv, const float* __restrict__ b2,
    float* __restrict__ out) {
  int wave = (blockIdx.x * 256 + threadIdx.x) >> 6;
  int lane = threadIdx.x & 63;
  if (wave >= GN) return;
  int d = wave;
  float di = dinv[d];
  float acc = h2[(size_t)d * 64 + lane] * di;
  int e0 = row[d], e1 = row[d + 1];
  int i = e0;
  for (; i + 4 <= e1; i += 4) {
    int s0 = srcs[i], s1 = srcs[i + 1], s2 = srcs[i + 2], s3 = srcs[i + 3];
    float w0 = dinv[s0], w1 = dinv[s1], w2 = dinv[s2], w3 = dinv[s3];
    float v0 = h2[(size_t)s0 * 64 + lane];
    float v1 = h2[(size_t)s1 * 64 + lane];
    float v2 = h2[(size_t)s2 * 64 + lane];
    float v3 = h2[(size_t)s3 * 64 + lane];
    acc += w0 * v0 + w1 * v1 + w2 * v2 + w3 * v3;
  }
  for (; i < e1; ++i) {
    int s = srcs[i];
    acc += dinv[s] * h2[(size_t)s * 64 + lane];
  }
  out[(size_t)d * 64 + lane] = acc * di + b2[lane];
}

__global__ __launch_bounds__(256) void bn_stats_kernel(const float* __restrict__ h,
    float* __restrict__ sum, float* __restrict__ sumsq) {
  int gt = blockIdx.x * 256 + threadIdx.x;   // 65536 threads = 512 row streams x 128 cols
  int c = gt & 127;
  int r = gt >> 7;
  float s = 0.f, ss = 0.f;
  for (; r < GN; r += 512) { float v = h[(size_t)r * 128 + c]; s += v; ss += v * v; }
  atomicAdd(&sum[c], s);
  atomicAdd(&sumsq[c], ss);
}

__global__ __launch_bounds__(128) void bn_final_kernel(const float* __restrict__ sum,
    const float* __restrict__ sumsq, const float* __restrict__ gamma,
    const float* __restrict__ beta, float* __restrict__ scale, float* __restrict__ shift) {
  int c = threadIdx.x;
  float mean = sum[c] * (1.0f / GN);
  float var = sumsq[c] * (1.0f / GN) - mean * mean;
  float istd = rsqrtf(var + 1e-5f);
  float g = gamma[c] * istd;
  scale[c] = g;
  shift[c] = beta[c] - mean * g;
}

extern "C" void kernel_launch(void* const* d_in, const int* in_sizes, int n_in,
                              void* d_out, int out_size, void* d_ws, size_t ws_size,
                              hipStream_t stream) {
  const float* x     = (const float*)d_in[0];
  const int*   e1    = (const int*)d_in[1];
  const int*   e2    = (const int*)d_in[2];
  const float* W1    = (const float*)d_in[3];
  const float* b1    = (const float*)d_in[4];
  const float* gamma = (const float*)d_in[5];
  const float* beta  = (const float*)d_in[6];
  const float* W2    = (const float*)d_in[7];
  const float* b2    = (const float*)d_in[8];

  float* out    = (float*)d_out;               // [N,64]
  float* hidden = out + (size_t)GN * OUTC;     // [N,128] second tuple element

  float* ws    = (float*)d_ws;
  float* h1    = ws + OFF_H1;
  float* h2    = ws + OFF_H2;
  float* dinv1 = ws + OFF_DINV1;
  float* dinv2 = ws + OFF_DINV2;
  int*   row1  = (int*)(ws + OFF_ROW1);
  int*   row2  = (int*)(ws + OFF_ROW2);
  int*   cur1  = (int*)(ws + OFF_CUR1);
  int*   cur2  = (int*)(ws + OFF_CUR2);
  int*   cnt1  = (int*)(ws + OFF_CNT1);
  int*   cnt2  = (int*)(ws + OFF_CNT2);
  float* bnbuf = ws + OFF_BN;
  int*   src1  = (int*)(ws + OFF_SRC1);
  int*   src2  = (int*)(ws + OFF_SRC2);
  int*   bsum  = (int*)(ws + OFF_BSUM);
  int*   bofs  = (int*)(ws + OFF_BOFS);

  // zero cnt1, cnt2, bn sums (contiguous region)
  hipMemsetAsync(ws + OFF_CNT1, 0, (size_t)(2 * GN + 512) * sizeof(float), stream);

  count_kernel<<<(GE + 255) / 256, 256, 0, stream>>>(e1, e2, cnt1, cnt2);
  scanA_kernel<<<2 * NB, 256, 0, stream>>>(cnt1, cnt2, bsum);
  scanB_kernel<<<1, 256, 0, stream>>>(bsum, bofs, row1, row2);
  scanC_kernel<<<2 * NB, 256, 0, stream>>>(cnt1, cnt2, bofs,
                                           row1, cur1, dinv1, row2, cur2, dinv2);
  fill_xcd_kernel<<<dim3(1024, 2), 256, 0, stream>>>(e1, e2, cur1, cur2, src1, src2);

  gemm1_kernel<<<dim3((GN + 31) / 32, 2), 256, 0, stream>>>(x, W1, h1);
  agg1_kernel<<<(GN * 64 + 255) / 256, 256, 0, stream>>>(h1, row1, src1, dinv1, b1, hidden);

  bn_stats_kernel<<<256, 256, 0, stream>>>(hidden, bnbuf, bnbuf + 128);
  bn_final_kernel<<<1, 128, 0, stream>>>(bnbuf, bnbuf + 128, gamma, beta,
                                         bnbuf + 256, bnbuf + 384);

  gemm2_kernel<<<dim3((GN + 31) / 32, 1), 256, 0, stream>>>(hidden, W2,
                                                            bnbuf + 256, bnbuf + 384, h2);
  agg2_kernel<<<(GN * 64 + 255) / 256, 256, 0, stream>>>(h2, row2, src2, dinv2, b2, out);
}